// Round 3
// baseline (201.071 us; speedup 1.0000x reference)
//
#include <hip/hip_runtime.h>
#include <stdint.h>

typedef __bf16 bf16;
typedef __attribute__((ext_vector_type(2))) __bf16 bf16x2;
typedef __attribute__((ext_vector_type(4))) __bf16 bf16x4;
typedef __attribute__((ext_vector_type(8))) __bf16 bf16x8;
typedef __attribute__((ext_vector_type(4))) float f32x4;
typedef __attribute__((ext_vector_type(4))) short s16x4;

#define B_  2
#define S_  2048
#define H_  1024
#define NH_ 16
#define HD_ 64

// async 16B global->LDS. LDS dest = wave-uniform base + lane*16.
__device__ __forceinline__ void glds16(const bf16* g, bf16* l) {
  __builtin_amdgcn_global_load_lds(
      (const __attribute__((address_space(1))) uint32_t*)g,
      (__attribute__((address_space(3))) uint32_t*)l, 16, 0, 0);
}

// PV MFMA: 16x16x16 bf16 — B operand layout (k=quad*4+e, col=l15) matches the
// S^T MFMA D layout exactly, so softmax P registers feed it with NO relayout.
__device__ __forceinline__ f32x4 pv_mfma(bf16x4 a, bf16x4 b, f32x4 c) {
#if __has_builtin(__builtin_amdgcn_mfma_f32_16x16x16bf16_1k)
  union U { bf16x4 h; s16x4 s; };
  U ua; ua.h = a;
  U ub; ub.h = b;
  return __builtin_amdgcn_mfma_f32_16x16x16bf16_1k(ua.s, ub.s, c, 0, 0, 0);
#else
  f32x4 d;
  asm volatile("v_mfma_f32_16x16x16_bf16 %0, %1, %2, %3\n\ts_nop 7\n\ts_nop 7"
               : "=v"(d) : "v"(a), "v"(b), "v"(c));
  return d;
#endif
}

// ---------------------------------------------------------------------------
// fp32 -> bf16 conversion: y=0 hidden_states, y=1..4 weight matrices.
// ---------------------------------------------------------------------------
__global__ __launch_bounds__(256) void cvt_f32_bf16(
    const float* __restrict__ s0, bf16* __restrict__ d0, int n0,
    const float* __restrict__ s1, bf16* __restrict__ d1,
    const float* __restrict__ s2, bf16* __restrict__ d2,
    const float* __restrict__ s3, bf16* __restrict__ d3,
    const float* __restrict__ s4, bf16* __restrict__ d4, int nw)
{
  const float* s; bf16* d; int n;
  switch (blockIdx.y) {
    case 0:  s = s0; d = d0; n = n0; break;
    case 1:  s = s1; d = d1; n = nw; break;
    case 2:  s = s2; d = d2; n = nw; break;
    case 3:  s = s3; d = d3; n = nw; break;
    default: s = s4; d = d4; n = nw; break;
  }
  const int i = (blockIdx.x * 256 + threadIdx.x) * 8;
  if (i >= n) return;
  float4 v0 = *(const float4*)(s + i);
  float4 v1 = *(const float4*)(s + i + 4);
  bf16x8 o;
  o[0] = (bf16)v0.x; o[1] = (bf16)v0.y; o[2] = (bf16)v0.z; o[3] = (bf16)v0.w;
  o[4] = (bf16)v1.x; o[5] = (bf16)v1.y; o[6] = (bf16)v1.z; o[7] = (bf16)v1.w;
  *(bf16x8*)(d + i) = o;
}

// ---------------------------------------------------------------------------
// GEMM: Y[m,n] = (sum_k X[m,k]*W[n,k] + bias[n]) * yscale, all-bf16, fp32 bias.
// yscale folds the attention softmax scale (1/sqrt(hd) * log2e) into Q for free.
// 128x128 tile, BK=32. Double-buffered LDS + glds16, ONE barrier per iter.
// ---------------------------------------------------------------------------
template <typename TY>
__global__ __launch_bounds__(256) void gemm_bt_bias(
    const bf16* __restrict__ X,
    const bf16* __restrict__ W0, const bf16* __restrict__ W1, const bf16* __restrict__ W2,
    const float* __restrict__ b0, const float* __restrict__ b1, const float* __restrict__ b2,
    TY* __restrict__ Y0, TY* __restrict__ Y1, TY* __restrict__ Y2,
    float ys0, float ys1, float ys2,
    int M, int N, int K)
{
  const bf16* W; const float* bias; TY* Y; float ysc;
  if (blockIdx.z == 0)      { W = W0; bias = b0; Y = Y0; ysc = ys0; }
  else if (blockIdx.z == 1) { W = W1; bias = b1; Y = Y1; ysc = ys1; }
  else                      { W = W2; bias = b2; Y = Y2; ysc = ys2; }

  __shared__ __align__(16) bf16 As[2][128 * 32];
  __shared__ __align__(16) bf16 Bs[2][128 * 32];

  const int tid  = threadIdx.x;
  const int lane = tid & 63;
  const int wave = tid >> 6;
  const int m0 = blockIdx.y * 128;
  const int n0 = blockIdx.x * 128;
  const int wm = (wave >> 1) * 64;
  const int wn = (wave & 1) * 64;

  const int r0 = tid >> 2,            c0 = (tid & 3) * 8;
  const int r1 = (256 + tid) >> 2,    c1 = ((256 + tid) & 3) * 8;
  const int cb0 = (wave * 64) * 8;
  const int cb1 = (256 + wave * 64) * 8;

  f32x4 acc[4][4] = {};

  glds16(X + (size_t)(m0 + r0) * K + c0, &As[0][cb0]);
  glds16(W + (size_t)(n0 + r0) * K + c0, &Bs[0][cb0]);
  glds16(X + (size_t)(m0 + r1) * K + c1, &As[0][cb1]);
  glds16(W + (size_t)(n0 + r1) * K + c1, &Bs[0][cb1]);

  int pb = 0;
  for (int k0 = 0; k0 < K; k0 += 32, pb ^= 1) {
    __syncthreads();

    if (k0 + 32 < K) {
      const int kn = k0 + 32;
      glds16(X + (size_t)(m0 + r0) * K + kn + c0, &As[pb ^ 1][cb0]);
      glds16(W + (size_t)(n0 + r0) * K + kn + c0, &Bs[pb ^ 1][cb0]);
      glds16(X + (size_t)(m0 + r1) * K + kn + c1, &As[pb ^ 1][cb1]);
      glds16(W + (size_t)(n0 + r1) * K + kn + c1, &Bs[pb ^ 1][cb1]);
    }

    bf16x8 a[4], b[4];
#pragma unroll
    for (int i = 0; i < 4; ++i)
      a[i] = *(const bf16x8*)&As[pb][(wm + i * 16 + (lane & 15)) * 32 + (lane >> 4) * 8];
#pragma unroll
    for (int i = 0; i < 4; ++i)
      b[i] = *(const bf16x8*)&Bs[pb][(wn + i * 16 + (lane & 15)) * 32 + (lane >> 4) * 8];
#pragma unroll
    for (int mi = 0; mi < 4; ++mi)
#pragma unroll
      for (int ni = 0; ni < 4; ++ni)
        acc[mi][ni] = __builtin_amdgcn_mfma_f32_16x16x32_bf16(a[mi], b[ni], acc[mi][ni], 0, 0, 0);
  }

#pragma unroll
  for (int mi = 0; mi < 4; ++mi) {
    const int row = m0 + wm + mi * 16 + (lane >> 4) * 4;
#pragma unroll
    for (int ni = 0; ni < 4; ++ni) {
      const int col = n0 + wn + ni * 16 + (lane & 15);
      const float bv = bias[col];
#pragma unroll
      for (int r = 0; r < 4; ++r)
        Y[(size_t)(row + r) * N + col] = (TY)((acc[mi][ni][r] + bv) * ysc);
    }
  }
}

// ---------------------------------------------------------------------------
// Flash attention, causal, transposed-score orientation, exp2-domain softmax.
// R3: softmax scale pre-folded into Q (GEMM epilogue). Defer-max with
//     algebraic fixup: p = exp2(s - mr) and PV run IMMEDIATELY; the max
//     tree + 2 shuffles run in parallel off the critical chain. Rare
//     overflow (mx > mr+8) is repaired after PV: O *= a, l *= a (exact,
//     since O' = a*(O_old + P·V)). mr starts at 0 so no -inf hazards.
//     Vt: unpadded [64][128] with chunk-XOR swizzle (both write & read
//     sides) -> 2-way max on PV b64 reads (free). Ks swizzle unchanged.
// ---------------------------------------------------------------------------

// one (q-tile x k-tile) step: QK^T -> online softmax -> PV, P in registers.
__device__ __forceinline__ void attn_tile_step(
    const bf16* Ksb, const bf16* Vtb, const bf16x8 bq[2], int qrow, int k0,
    bool maskit, float& mr, float& lr, f32x4 oacc[4], int l15, int quad)
{
  // ---- S^T = K Q^T ----  (Q pre-scaled by 0.125*log2e in the QKV GEMM)
  f32x4 sacc[8] = {};
  __builtin_amdgcn_s_setprio(1);
#pragma unroll
  for (int ks = 0; ks < 2; ++ks) {
#pragma unroll
    for (int mb = 0; mb < 8; ++mb) {
      const int row = mb * 16 + l15;
      const int ch  = (ks * 4 + quad) ^ (l15 & 7);   // XOR de-swizzle
      bf16x8 ak = *(const bf16x8*)&Ksb[row * 64 + ch * 8];
      sacc[mb] = __builtin_amdgcn_mfma_f32_16x16x32_bf16(ak, bq[ks], sacc[mb], 0, 0, 0);
    }
  }
  __builtin_amdgcn_s_setprio(0);

  // causal mask (only on the final k-tile of this q-tile)
  if (maskit) {
#pragma unroll
    for (int mb = 0; mb < 8; ++mb) {
      const int kb = k0 + mb * 16 + quad * 4;
#pragma unroll
      for (int r = 0; r < 4; ++r)
        if (kb + r > qrow) sacc[mb][r] = -1e30f;
    }
  }

  // max tree + shuffles — runs in PARALLEL with the exp2/PV chain below
  float mx = -1e30f;
#pragma unroll
  for (int mb = 0; mb < 8; ++mb)
    mx = fmaxf(mx, fmaxf(fmaxf(sacc[mb][0], sacc[mb][1]),
                         fmaxf(sacc[mb][2], sacc[mb][3])));
  mx = fmaxf(mx, __shfl_xor(mx, 16, 64));
  mx = fmaxf(mx, __shfl_xor(mx, 32, 64));

  // speculative exp2 with CURRENT mr (no dependence on mx)
  float sum = 0.0f;
  bf16x4 pwv[8];
#pragma unroll
  for (int mb = 0; mb < 8; ++mb) {
    bf16x4 pw;
#pragma unroll
    for (int r = 0; r < 4; ++r) {
      const float p = __builtin_amdgcn_exp2f(sacc[mb][r] - mr);
      sum += p;
      pw[r] = (bf16)p;
    }
    pwv[mb] = pw;
  }
  sum += __shfl_xor(sum, 16, 64);
  sum += __shfl_xor(sum, 32, 64);

  // ---- O^T += V^T P^T : 16x16x16, P direct from registers ----
  __builtin_amdgcn_s_setprio(1);
#pragma unroll
  for (int mb = 0; mb < 8; ++mb) {
#pragma unroll
    for (int db = 0; db < 4; ++db) {
      const int vch = ((mb * 4 + quad) ^ (l15 & 7)) * 4;
      bf16x4 av = *(const bf16x4*)&Vtb[(db * 16 + l15) * 128 + vch];
      oacc[db] = pv_mfma(av, pwv[mb], oacc[db]);
    }
  }
  __builtin_amdgcn_s_setprio(0);

  lr += sum;
  // rare fixup: rescale AFTER accumulation (exact: O' = a*(O_old + P·V))
  if (!__all(mx <= mr + 8.0f)) {
    const float mnew  = fmaxf(mr, mx);
    const float alpha = __builtin_amdgcn_exp2f(mr - mnew);
    lr *= alpha;
#pragma unroll
    for (int db = 0; db < 4; ++db)
#pragma unroll
      for (int r = 0; r < 4; ++r) oacc[db][r] *= alpha;
    mr = mnew;
  }
}

__global__ __launch_bounds__(256, 2) void attn_causal(
    const bf16* __restrict__ Q, const bf16* __restrict__ K,
    const bf16* __restrict__ V, bf16* __restrict__ O)
{
  // XCD-chunked decode: all 16 pair-blocks of a bh land on one XCD (lin%8).
  const int lin  = blockIdx.x;               // 0..511
  const int slot = lin >> 3;                 // 0..63
  const int bh   = (lin & 7) * 4 + (slot >> 4);
  const int pair = slot & 15;
  const int b    = bh >> 4;
  const int h    = bh & 15;

  const int tid  = threadIdx.x;
  const int lane = tid & 63;
  const int wave = tid >> 6;
  const int quad = lane >> 4;
  const int l15  = lane & 15;
  const size_t headoff = (size_t)b * S_ * H_ + (size_t)h * HD_;
  const bf16* Kp = K + headoff;
  const bf16* Vp = V + headoff;

  __shared__ __align__(16) bf16 Ks[2][128 * 64];    // unpadded, XOR-swizzled
  __shared__ __align__(16) bf16 Vt[2][64 * 128];    // Vt[d][key], XOR-swizzled

  const int qlo = pair, qhi = 31 - pair;
  const int nl  = (qlo >> 1) + 1;      // 1..8
  const int nh  = (qhi >> 1) + 1;      // 9..16  (nl < nh always)
  const int qrowL = qlo * 64 + wave * 16 + l15;
  const int qrowH = qhi * 64 + wave * 16 + l15;

  // Q fragments in registers for the whole block (pre-scaled by QKV GEMM)
  bf16x8 bqL[2], bqH[2];
  bqL[0] = *(const bf16x8*)(Q + headoff + (size_t)qrowL * H_ + quad * 8);
  bqL[1] = *(const bf16x8*)(Q + headoff + (size_t)qrowL * H_ + 32 + quad * 8);
  bqH[0] = *(const bf16x8*)(Q + headoff + (size_t)qrowH * H_ + quad * 8);
  bqH[1] = *(const bf16x8*)(Q + headoff + (size_t)qrowH * H_ + 32 + quad * 8);

  // --- staging helpers ---
  // K: glds16, LDS linear in chunk order, source chunk XOR-pre-swizzled so
  //   LDS chunk (row, c') holds global chunk c'^(row&7)  (read undoes it).
  const int vr = lane * 2;          // V: two adjacent key rows per thread
  const int vc = wave * 16;         //    16 of 64 head dims per wave

#define STAGE_K(k0_, buf_)                                                  \
  {                                                                         \
    _Pragma("unroll")                                                       \
    for (int i = 0; i < 4; ++i) {                                           \
      const int n = i * 256 + tid;                                          \
      const int row = n >> 3;                                               \
      const int cg  = (n & 7) ^ (row & 7);                                  \
      glds16(Kp + (size_t)((k0_) + row) * H_ + cg * 8,                      \
             &Ks[buf_][(i * 256 + wave * 64) * 8]);                         \
    }                                                                       \
  }

#define LOAD_V(k0_)                                                         \
  {                                                                         \
    vreg[0] = *(const bf16x8*)(Vp + (size_t)((k0_) + vr) * H_ + vc);        \
    vreg[1] = *(const bf16x8*)(Vp + (size_t)((k0_) + vr) * H_ + vc + 8);    \
    vreg[2] = *(const bf16x8*)(Vp + (size_t)((k0_) + vr + 1) * H_ + vc);    \
    vreg[3] = *(const bf16x8*)(Vp + (size_t)((k0_) + vr + 1) * H_ + vc + 8);\
  }

// Vt write with chunk-XOR swizzle: chunk (4 elems) index = (vr>>2) ^ (row&7).
// rows vc+e and vc+8+e share (row&7)==e, so one swizzled offset serves both.
#define WRITE_V(buf_)                                                       \
  {                                                                         \
    _Pragma("unroll")                                                       \
    for (int e = 0; e < 8; ++e) {                                           \
      const int sw = (((vr >> 2) ^ e) * 4) + (vr & 3);                      \
      bf16x2 p0; p0[0] = vreg[0][e]; p0[1] = vreg[2][e];                    \
      *(bf16x2*)&Vt[buf_][(vc + e) * 128 + sw] = p0;                        \
      bf16x2 p1; p1[0] = vreg[1][e]; p1[1] = vreg[3][e];                    \
      *(bf16x2*)&Vt[buf_][(vc + 8 + e) * 128 + sw] = p1;                    \
    }                                                                       \
  }

  bf16x8 vreg[4];

  // prologue: tile 0 -> buf 0
  STAGE_K(0, 0);
  LOAD_V(0);
  WRITE_V(0);
  __syncthreads();

  float mrL = 0.0f, lrL = 0.0f, mrH = 0.0f, lrH = 0.0f;
  f32x4 oL[4] = {}, oH[4] = {};

  for (int it = 0; it < nh; ++it) {
    const int c = it & 1;
    const bool pre = (it + 1 < nh);

    if (pre) {                       // prefetch tile it+1 into buf c^1
      STAGE_K((it + 1) * 128, c ^ 1);
      LOAD_V((it + 1) * 128);
    }

    attn_tile_step(Ks[c], Vt[c], bqH, qrowH, it * 128, it == nh - 1,
                   mrH, lrH, oH, l15, quad);
    if (it < nl)
      attn_tile_step(Ks[c], Vt[c], bqL, qrowL, it * 128, it == nl - 1,
                     mrL, lrL, oL, l15, quad);

    if (pre) {
      WRITE_V(c ^ 1);                // reg->LDS after compute (issue-early/write-late)
      __syncthreads();               // drains glds + V writes; publishes buf c^1
    }
  }

  // epilogues
  const float invL = 1.0f / lrL;
#pragma unroll
  for (int db = 0; db < 4; ++db) {
    bf16x4 o;
#pragma unroll
    for (int r = 0; r < 4; ++r) o[r] = (bf16)(oL[db][r] * invL);
    *(bf16x4*)(O + headoff + (size_t)qrowL * H_ + db * 16 + quad * 4) = o;
  }
  const float invH = 1.0f / lrH;
#pragma unroll
  for (int db = 0; db < 4; ++db) {
    bf16x4 o;
#pragma unroll
    for (int r = 0; r < 4; ++r) o[r] = (bf16)(oH[db][r] * invH);
    *(bf16x4*)(O + headoff + (size_t)qrowH * H_ + db * 16 + quad * 4) = o;
  }
#undef STAGE_K
#undef LOAD_V
#undef WRITE_V
}

extern "C" void kernel_launch(void* const* d_in, const int* in_sizes, int n_in,
                              void* d_out, int out_size, void* d_ws, size_t ws_size,
                              hipStream_t stream) {
  const float* hs = (const float*)d_in[0];
  const float* Wq = (const float*)d_in[1]; const float* bq = (const float*)d_in[2];
  const float* Wk = (const float*)d_in[3]; const float* bk = (const float*)d_in[4];
  const float* Wv = (const float*)d_in[5]; const float* bv = (const float*)d_in[6];
  const float* Wo = (const float*)d_in[7]; const float* bo = (const float*)d_in[8];
  float* out = (float*)d_out;

  const size_t elems = (size_t)B_ * S_ * H_;   // 4,194,304
  const size_t wel   = (size_t)H_ * H_;        // 1,048,576
  bf16* hsb = (bf16*)d_ws;      // read only by QKV GEMM
  bf16* AO  = hsb;              // written by attn (hsb dead by then)
  bf16* Wqb = hsb + elems;
  bf16* Wkb = Wqb + wel;
  bf16* Wvb = Wkb + wel;
  bf16* Wob = Wvb + wel;
  bf16* Qw  = Wob + wel;
  bf16* Kw  = Qw + elems;
  bf16* Vw  = Kw + elems;

  cvt_f32_bf16<<<dim3(2048, 5), dim3(256), 0, stream>>>(
      hs, hsb, (int)elems, Wq, Wqb, Wk, Wkb, Wv, Wvb, Wo, Wob, (int)wel);

  const int M = B_ * S_;   // 4096
  const float QSCL = 0.125f * 1.44269504f;   // (1/sqrt(64)) * log2(e)
  gemm_bt_bias<bf16><<<dim3(H_ / 128, M / 128, 3), dim3(256), 0, stream>>>(
      hsb, Wqb, Wkb, Wvb, bq, bk, bv, Qw, Kw, Vw, QSCL, 1.0f, 1.0f, M, H_, H_);

  attn_causal<<<dim3(512), dim3(256), 0, stream>>>(Qw, Kw, Vw, AO);

  gemm_bt_bias<float><<<dim3(H_ / 128, M / 128, 1), dim3(256), 0, stream>>>(
      AO, Wob, Wob, Wob, bo, bo, bo, out, out, out, 1.0f, 1.0f, 1.0f, M, H_, H_);
}

// Round 4
// 200.719 us; speedup vs baseline: 1.0018x; 1.0018x over previous
//
#include <hip/hip_runtime.h>
#include <stdint.h>

typedef __bf16 bf16;
typedef __attribute__((ext_vector_type(2))) __bf16 bf16x2;
typedef __attribute__((ext_vector_type(4))) __bf16 bf16x4;
typedef __attribute__((ext_vector_type(8))) __bf16 bf16x8;
typedef __attribute__((ext_vector_type(4))) float f32x4;
typedef __attribute__((ext_vector_type(4))) short s16x4;

#define B_  2
#define S_  2048
#define H_  1024
#define NH_ 16
#define HD_ 64
#define RS  3072    // fused QKV row stride

// async 16B global->LDS. LDS dest = wave-uniform base + lane*16.
__device__ __forceinline__ void glds16(const bf16* g, bf16* l) {
  __builtin_amdgcn_global_load_lds(
      (const __attribute__((address_space(1))) uint32_t*)g,
      (__attribute__((address_space(3))) uint32_t*)l, 16, 0, 0);
}

// PV MFMA: 16x16x16 bf16 — B operand layout (k=quad*4+e, col=l15) matches the
// S^T MFMA D layout exactly, so softmax P registers feed it with NO relayout.
__device__ __forceinline__ f32x4 pv_mfma(bf16x4 a, bf16x4 b, f32x4 c) {
#if __has_builtin(__builtin_amdgcn_mfma_f32_16x16x16bf16_1k)
  union U { bf16x4 h; s16x4 s; };
  U ua; ua.h = a;
  U ub; ub.h = b;
  return __builtin_amdgcn_mfma_f32_16x16x16bf16_1k(ua.s, ub.s, c, 0, 0, 0);
#else
  f32x4 d;
  asm volatile("v_mfma_f32_16x16x16_bf16 %0, %1, %2, %3\n\ts_nop 7\n\ts_nop 7"
               : "=v"(d) : "v"(a), "v"(b), "v"(c));
  return d;
#endif
}

// ---------------------------------------------------------------------------
// fp32 -> bf16 conversion: y=0 hidden_states, y=1..4 weight matrices.
// ---------------------------------------------------------------------------
__global__ __launch_bounds__(256) void cvt_f32_bf16(
    const float* __restrict__ s0, bf16* __restrict__ d0, int n0,
    const float* __restrict__ s1, bf16* __restrict__ d1,
    const float* __restrict__ s2, bf16* __restrict__ d2,
    const float* __restrict__ s3, bf16* __restrict__ d3,
    const float* __restrict__ s4, bf16* __restrict__ d4, int nw)
{
  const float* s; bf16* d; int n;
  switch (blockIdx.y) {
    case 0:  s = s0; d = d0; n = n0; break;
    case 1:  s = s1; d = d1; n = nw; break;
    case 2:  s = s2; d = d2; n = nw; break;
    case 3:  s = s3; d = d3; n = nw; break;
    default: s = s4; d = d4; n = nw; break;
  }
  const int i = (blockIdx.x * 256 + threadIdx.x) * 8;
  if (i >= n) return;
  float4 v0 = *(const float4*)(s + i);
  float4 v1 = *(const float4*)(s + i + 4);
  bf16x8 o;
  o[0] = (bf16)v0.x; o[1] = (bf16)v0.y; o[2] = (bf16)v0.z; o[3] = (bf16)v0.w;
  o[4] = (bf16)v1.x; o[5] = (bf16)v1.y; o[6] = (bf16)v1.z; o[7] = (bf16)v1.w;
  *(bf16x8*)(d + i) = o;
}

// ---------------------------------------------------------------------------
// Fused QKV GEMM, 8-phase 256x256xBK64 schedule (T2+T3+T4+T5 port).
// Ycat[m][0..3072) = (X[m]·Wc[n]^T + bias[n]) * ysc_seg.  Wc = [Wq;Wk;Wv]
// (contiguous in workspace).  512 thr / 8 waves (2Mx4N), wave tile 128x64,
// 64 MFMA per K-tile per wave.  LDS 128 KiB: A,B double-buffered 256x64.
// Per tile: P1{read A-lo+B-lo(12), stage A(t+1)} P2{read B-hi(4), stage
// B(t+1)} P3{read A-hi(8)} P4{vmcnt-drain} — each phase: raw s_barrier,
// setprio(1) around 16-MFMA cluster, s_barrier.  The 8 stage ops issued at
// P1/P2 have >=2 phases (~1200cy) of MFMA cover before the once-per-tile
// vmcnt(0) drain -> HBM latency pre-covered (the 128x2-barrier disease
// amortized 4x).  LDS XOR swizzle kc^=(row&7): inverse-swizzled GLOBAL
// source (glds16 dest linear, rule 21) + swizzled read -> conflict-free
// quarter-wave b128 reads.
// ---------------------------------------------------------------------------
__global__ __launch_bounds__(512, 2) void gemm_qkv_8ph(
    const bf16* __restrict__ X,      // [4096][1024]
    const bf16* __restrict__ Wc,     // [3072][1024]
    const float* __restrict__ bq, const float* __restrict__ bk,
    const float* __restrict__ bv,
    bf16* __restrict__ Y,            // [4096][3072]
    float qscl)
{
  constexpr int K  = 1024;
  constexpr int NT = K / 64;         // 16 K-tiles

  __shared__ __align__(16) bf16 As[2][256 * 64];
  __shared__ __align__(16) bf16 Bs[2][256 * 64];

  // bijective XCD swizzle (192 = 8 * 24), then bx-major within chunk
  const int f   = blockIdx.x;
  const int swz = (f & 7) * 24 + (f >> 3);
  const int by  = swz / 12, bx = swz % 12;
  const int m0  = by * 256, n0 = bx * 256;

  const int tid  = threadIdx.x;
  const int lane = tid & 63;
  const int wave = tid >> 6;
  const int quad = lane >> 4;
  const int l15  = lane & 15;
  const int wm   = (wave >> 2) * 128;
  const int wn   = (wave & 3) * 64;

  const int r0  = tid >> 3;          // staging row within 64-row group
  const int kc0 = tid & 7;           // staging 16B-chunk within row

  const bf16* Xb = X  + (size_t)m0 * K;
  const bf16* Wb = Wc + (size_t)n0 * K;

  f32x4 acc[8][4] = {};

#define SBAR() asm volatile("s_barrier" ::: "memory")
#define VM0()  asm volatile("s_waitcnt vmcnt(0)" ::: "memory")
#define STG(MAT, G, cb_, h)                                                 \
  { _Pragma("unroll") for (int s = 0; s < 2; ++s) {                         \
      const int row = (h) * 128 + s * 64 + r0;                              \
      const int sc  = kc0 ^ (row & 7);                                      \
      glds16((G) + (size_t)row * K + sc * 8,                                \
             &MAT[cb_][((h) * 1024 + s * 512 + wave * 64) * 8]); } }
#define RA(mi, ks) (*(const bf16x8*)&As[cb][(wm + (mi) * 16 + l15) * 64 +   \
                     ((((ks) * 4 + quad)) ^ (l15 & 7)) * 8])
#define RB(ni, ks) (*(const bf16x8*)&Bs[cb][(wn + (ni) * 16 + l15) * 64 +   \
                     ((((ks) * 4 + quad)) ^ (l15 & 7)) * 8])
#define MFMA(d, x, y) d = __builtin_amdgcn_mfma_f32_16x16x32_bf16(x, y, d, 0, 0, 0)

  // prologue: tile 0 into buf 0
  STG(As, Xb, 0, 0); STG(As, Xb, 0, 1);
  STG(Bs, Wb, 0, 0); STG(Bs, Wb, 0, 1);
  VM0();
  SBAR();

  for (int t = 0; t < NT; ++t) {
    const int cb = t & 1, sb = cb ^ 1;
    const bf16* Xn = Xb + (t + 1) * 64;
    const bf16* Wn = Wb + (t + 1) * 64;
    const bool pre = (t + 1 < NT);

    bf16x8 a[4][2], b[4][2];

    // ---- P1: read A-lo (8) + B-lo (4); stage A(t+1) ----
#pragma unroll
    for (int mi = 0; mi < 4; ++mi) { a[mi][0] = RA(mi, 0); a[mi][1] = RA(mi, 1); }
#pragma unroll
    for (int ni = 0; ni < 2; ++ni) { b[ni][0] = RB(ni, 0); b[ni][1] = RB(ni, 1); }
    if (pre) { STG(As, Xn, sb, 0); STG(As, Xn, sb, 1); }
    SBAR();
    __builtin_amdgcn_s_setprio(1);
#pragma unroll
    for (int mi = 0; mi < 4; ++mi)
#pragma unroll
      for (int ni = 0; ni < 2; ++ni) {
        MFMA(acc[mi][ni], a[mi][0], b[ni][0]);
        MFMA(acc[mi][ni], a[mi][1], b[ni][1]);
      }
    __builtin_amdgcn_s_setprio(0);
    SBAR();

    // ---- P2: read B-hi (4); stage B(t+1) ----
#pragma unroll
    for (int ni = 2; ni < 4; ++ni) { b[ni][0] = RB(ni, 0); b[ni][1] = RB(ni, 1); }
    if (pre) { STG(Bs, Wn, sb, 0); STG(Bs, Wn, sb, 1); }
    SBAR();
    __builtin_amdgcn_s_setprio(1);
#pragma unroll
    for (int mi = 0; mi < 4; ++mi)
#pragma unroll
      for (int ni = 2; ni < 4; ++ni) {
        MFMA(acc[mi][ni], a[mi][0], b[ni][0]);
        MFMA(acc[mi][ni], a[mi][1], b[ni][1]);
      }
    __builtin_amdgcn_s_setprio(0);
    SBAR();

    // ---- P3: read A-hi (8) ----
#pragma unroll
    for (int mi = 0; mi < 4; ++mi) { a[mi][0] = RA(mi + 4, 0); a[mi][1] = RA(mi + 4, 1); }
    SBAR();
    __builtin_amdgcn_s_setprio(1);
#pragma unroll
    for (int mi = 0; mi < 4; ++mi)
#pragma unroll
      for (int ni = 0; ni < 2; ++ni) {
        MFMA(acc[mi + 4][ni], a[mi][0], b[ni][0]);
        MFMA(acc[mi + 4][ni], a[mi][1], b[ni][1]);
      }
    __builtin_amdgcn_s_setprio(0);
    SBAR();

    // ---- P4: register-only MFMA; once-per-tile counted drain ----
    __builtin_amdgcn_s_setprio(1);
#pragma unroll
    for (int mi = 0; mi < 4; ++mi)
#pragma unroll
      for (int ni = 2; ni < 4; ++ni) {
        MFMA(acc[mi + 4][ni], a[mi][0], b[ni][0]);
        MFMA(acc[mi + 4][ni], a[mi][1], b[ni][1]);
      }
    __builtin_amdgcn_s_setprio(0);
    VM0();        // next tile's 8 stage ops (issued P1/P2, >=2 phases cover)
    SBAR();       // publishes buf sb for tile t+1
  }

  // epilogue: bias + per-segment scale (tile never straddles a segment)
  const int seg = bx >> 2;
  const float* bias = seg == 0 ? bq : (seg == 1 ? bk : bv);
  const float ysc = seg == 0 ? qscl : 1.0f;
#pragma unroll
  for (int mi = 0; mi < 8; ++mi) {
    const int row = m0 + wm + mi * 16 + quad * 4;
#pragma unroll
    for (int ni = 0; ni < 4; ++ni) {
      const int col = n0 + wn + ni * 16 + l15;
      const float bvv = bias[col & 1023];
#pragma unroll
      for (int r = 0; r < 4; ++r)
        Y[(size_t)(row + r) * RS + col] = (bf16)((acc[mi][ni][r] + bvv) * ysc);
    }
  }
#undef SBAR
#undef VM0
#undef STG
#undef RA
#undef RB
#undef MFMA
}

// ---------------------------------------------------------------------------
// GEMM: Y[m,n] = (sum_k X[m,k]*W[n,k] + bias[n]) * ysc (O-projection).
// 128x128 tile, BK=32. Double-buffered LDS + glds16, ONE barrier per iter.
// ---------------------------------------------------------------------------
template <typename TY>
__global__ __launch_bounds__(256) void gemm_bt_bias(
    const bf16* __restrict__ X,
    const bf16* __restrict__ W0, const bf16* __restrict__ W1, const bf16* __restrict__ W2,
    const float* __restrict__ b0, const float* __restrict__ b1, const float* __restrict__ b2,
    TY* __restrict__ Y0, TY* __restrict__ Y1, TY* __restrict__ Y2,
    float ys0, float ys1, float ys2,
    int M, int N, int K)
{
  const bf16* W; const float* bias; TY* Y; float ysc;
  if (blockIdx.z == 0)      { W = W0; bias = b0; Y = Y0; ysc = ys0; }
  else if (blockIdx.z == 1) { W = W1; bias = b1; Y = Y1; ysc = ys1; }
  else                      { W = W2; bias = b2; Y = Y2; ysc = ys2; }

  __shared__ __align__(16) bf16 As[2][128 * 32];
  __shared__ __align__(16) bf16 Bs[2][128 * 32];

  const int tid  = threadIdx.x;
  const int lane = tid & 63;
  const int wave = tid >> 6;
  const int m0 = blockIdx.y * 128;
  const int n0 = blockIdx.x * 128;
  const int wm = (wave >> 1) * 64;
  const int wn = (wave & 1) * 64;

  const int r0 = tid >> 2,            c0 = (tid & 3) * 8;
  const int r1 = (256 + tid) >> 2,    c1 = ((256 + tid) & 3) * 8;
  const int cb0 = (wave * 64) * 8;
  const int cb1 = (256 + wave * 64) * 8;

  f32x4 acc[4][4] = {};

  glds16(X + (size_t)(m0 + r0) * K + c0, &As[0][cb0]);
  glds16(W + (size_t)(n0 + r0) * K + c0, &Bs[0][cb0]);
  glds16(X + (size_t)(m0 + r1) * K + c1, &As[0][cb1]);
  glds16(W + (size_t)(n0 + r1) * K + c1, &Bs[0][cb1]);

  int pb = 0;
  for (int k0 = 0; k0 < K; k0 += 32, pb ^= 1) {
    __syncthreads();

    if (k0 + 32 < K) {
      const int kn = k0 + 32;
      glds16(X + (size_t)(m0 + r0) * K + kn + c0, &As[pb ^ 1][cb0]);
      glds16(W + (size_t)(n0 + r0) * K + kn + c0, &Bs[pb ^ 1][cb0]);
      glds16(X + (size_t)(m0 + r1) * K + kn + c1, &As[pb ^ 1][cb1]);
      glds16(W + (size_t)(n0 + r1) * K + kn + c1, &Bs[pb ^ 1][cb1]);
    }

    bf16x8 a[4], b[4];
#pragma unroll
    for (int i = 0; i < 4; ++i)
      a[i] = *(const bf16x8*)&As[pb][(wm + i * 16 + (lane & 15)) * 32 + (lane >> 4) * 8];
#pragma unroll
    for (int i = 0; i < 4; ++i)
      b[i] = *(const bf16x8*)&Bs[pb][(wn + i * 16 + (lane & 15)) * 32 + (lane >> 4) * 8];
#pragma unroll
    for (int mi = 0; mi < 4; ++mi)
#pragma unroll
      for (int ni = 0; ni < 4; ++ni)
        acc[mi][ni] = __builtin_amdgcn_mfma_f32_16x16x32_bf16(a[mi], b[ni], acc[mi][ni], 0, 0, 0);
  }

#pragma unroll
  for (int mi = 0; mi < 4; ++mi) {
    const int row = m0 + wm + mi * 16 + (lane >> 4) * 4;
#pragma unroll
    for (int ni = 0; ni < 4; ++ni) {
      const int col = n0 + wn + ni * 16 + (lane & 15);
      const float bv = bias[col];
#pragma unroll
      for (int r = 0; r < 4; ++r)
        Y[(size_t)(row + r) * N + col] = (TY)((acc[mi][ni][r] + bv) * ysc);
    }
  }
}

// ---------------------------------------------------------------------------
// Flash attention, causal, transposed-score orientation, exp2-domain softmax.
// Reads Q/K/V from the fused Ycat[4096][3072] (Q at col 0, K at 1024, V at
// 2048).  Block = paired q-tiles (p, 31-p) sharing one merged k-loop;
// double-buffered K/V, one barrier per iter; P in registers (16x16x16 PV);
// defer-max with algebraic post-PV fixup; Q pre-scaled by QKV GEMM.
// ---------------------------------------------------------------------------
__device__ __forceinline__ void attn_tile_step(
    const bf16* Ksb, const bf16* Vtb, const bf16x8 bq[2], int qrow, int k0,
    bool maskit, float& mr, float& lr, f32x4 oacc[4], int l15, int quad)
{
  // ---- S^T = K Q^T ----  (Q pre-scaled by 0.125*log2e in the QKV GEMM)
  f32x4 sacc[8] = {};
  __builtin_amdgcn_s_setprio(1);
#pragma unroll
  for (int ks = 0; ks < 2; ++ks) {
#pragma unroll
    for (int mb = 0; mb < 8; ++mb) {
      const int row = mb * 16 + l15;
      const int ch  = (ks * 4 + quad) ^ (l15 & 7);   // XOR de-swizzle
      bf16x8 ak = *(const bf16x8*)&Ksb[row * 64 + ch * 8];
      sacc[mb] = __builtin_amdgcn_mfma_f32_16x16x32_bf16(ak, bq[ks], sacc[mb], 0, 0, 0);
    }
  }
  __builtin_amdgcn_s_setprio(0);

  // causal mask (only on the final k-tile of this q-tile)
  if (maskit) {
#pragma unroll
    for (int mb = 0; mb < 8; ++mb) {
      const int kb = k0 + mb * 16 + quad * 4;
#pragma unroll
      for (int r = 0; r < 4; ++r)
        if (kb + r > qrow) sacc[mb][r] = -1e30f;
    }
  }

  // max tree + shuffles — runs in PARALLEL with the exp2/PV chain below
  float mx = -1e30f;
#pragma unroll
  for (int mb = 0; mb < 8; ++mb)
    mx = fmaxf(mx, fmaxf(fmaxf(sacc[mb][0], sacc[mb][1]),
                         fmaxf(sacc[mb][2], sacc[mb][3])));
  mx = fmaxf(mx, __shfl_xor(mx, 16, 64));
  mx = fmaxf(mx, __shfl_xor(mx, 32, 64));

  // speculative exp2 with CURRENT mr (no dependence on mx)
  float sum = 0.0f;
  bf16x4 pwv[8];
#pragma unroll
  for (int mb = 0; mb < 8; ++mb) {
    bf16x4 pw;
#pragma unroll
    for (int r = 0; r < 4; ++r) {
      const float p = __builtin_amdgcn_exp2f(sacc[mb][r] - mr);
      sum += p;
      pw[r] = (bf16)p;
    }
    pwv[mb] = pw;
  }
  sum += __shfl_xor(sum, 16, 64);
  sum += __shfl_xor(sum, 32, 64);

  // ---- O^T += V^T P^T : 16x16x16, P direct from registers ----
  __builtin_amdgcn_s_setprio(1);
#pragma unroll
  for (int mb = 0; mb < 8; ++mb) {
#pragma unroll
    for (int db = 0; db < 4; ++db) {
      const int vch = ((mb * 4 + quad) ^ (l15 & 7)) * 4;
      bf16x4 av = *(const bf16x4*)&Vtb[(db * 16 + l15) * 128 + vch];
      oacc[db] = pv_mfma(av, pwv[mb], oacc[db]);
    }
  }
  __builtin_amdgcn_s_setprio(0);

  lr += sum;
  // rare fixup: rescale AFTER accumulation (exact: O' = a*(O_old + P·V))
  if (!__all(mx <= mr + 8.0f)) {
    const float mnew  = fmaxf(mr, mx);
    const float alpha = __builtin_amdgcn_exp2f(mr - mnew);
    lr *= alpha;
#pragma unroll
    for (int db = 0; db < 4; ++db)
#pragma unroll
      for (int r = 0; r < 4; ++r) oacc[db][r] *= alpha;
    mr = mnew;
  }
}

__global__ __launch_bounds__(256, 2) void attn_causal(
    const bf16* __restrict__ QKV,    // Ycat [B*S][3072]
    bf16* __restrict__ O)            // [B*S][1024]
{
  // XCD-chunked decode: all 16 pair-blocks of a bh land on one XCD (lin%8).
  const int lin  = blockIdx.x;               // 0..511
  const int slot = lin >> 3;                 // 0..63
  const int bh   = (lin & 7) * 4 + (slot >> 4);
  const int pair = slot & 15;
  const int b    = bh >> 4;
  const int h    = bh & 15;

  const int tid  = threadIdx.x;
  const int lane = tid & 63;
  const int wave = tid >> 6;
  const int quad = lane >> 4;
  const int l15  = lane & 15;
  const size_t headq = (size_t)b * S_ * RS + (size_t)h * HD_;
  const size_t heado = (size_t)b * S_ * H_ + (size_t)h * HD_;
  const bf16* Qp = QKV + headq;
  const bf16* Kp = QKV + headq + 1024;
  const bf16* Vp = QKV + headq + 2048;

  __shared__ __align__(16) bf16 Ks[2][128 * 64];    // unpadded, XOR-swizzled
  __shared__ __align__(16) bf16 Vt[2][64 * 128];    // Vt[d][key], XOR-swizzled

  const int qlo = pair, qhi = 31 - pair;
  const int nl  = (qlo >> 1) + 1;      // 1..8
  const int nh  = (qhi >> 1) + 1;      // 9..16  (nl < nh always)
  const int qrowL = qlo * 64 + wave * 16 + l15;
  const int qrowH = qhi * 64 + wave * 16 + l15;

  // Q fragments in registers for the whole block (pre-scaled by QKV GEMM)
  bf16x8 bqL[2], bqH[2];
  bqL[0] = *(const bf16x8*)(Qp + (size_t)qrowL * RS + quad * 8);
  bqL[1] = *(const bf16x8*)(Qp + (size_t)qrowL * RS + 32 + quad * 8);
  bqH[0] = *(const bf16x8*)(Qp + (size_t)qrowH * RS + quad * 8);
  bqH[1] = *(const bf16x8*)(Qp + (size_t)qrowH * RS + 32 + quad * 8);

  const int vr = lane * 2;          // V: two adjacent key rows per thread
  const int vc = wave * 16;         //    16 of 64 head dims per wave

#define STAGE_K(k0_, buf_)                                                  \
  {                                                                         \
    _Pragma("unroll")                                                       \
    for (int i = 0; i < 4; ++i) {                                           \
      const int n = i * 256 + tid;                                          \
      const int row = n >> 3;                                               \
      const int cg  = (n & 7) ^ (row & 7);                                  \
      glds16(Kp + (size_t)((k0_) + row) * RS + cg * 8,                      \
             &Ks[buf_][(i * 256 + wave * 64) * 8]);                         \
    }                                                                       \
  }

#define LOAD_V(k0_)                                                         \
  {                                                                         \
    vreg[0] = *(const bf16x8*)(Vp + (size_t)((k0_) + vr) * RS + vc);        \
    vreg[1] = *(const bf16x8*)(Vp + (size_t)((k0_) + vr) * RS + vc + 8);    \
    vreg[2] = *(const bf16x8*)(Vp + (size_t)((k0_) + vr + 1) * RS + vc);    \
    vreg[3] = *(const bf16x8*)(Vp + (size_t)((k0_) + vr + 1) * RS + vc + 8);\
  }

#define WRITE_V(buf_)                                                       \
  {                                                                         \
    _Pragma("unroll")                                                       \
    for (int e = 0; e < 8; ++e) {                                           \
      const int sw = (((vr >> 2) ^ e) * 4) + (vr & 3);                      \
      bf16x2 p0; p0[0] = vreg[0][e]; p0[1] = vreg[2][e];                    \
      *(bf16x2*)&Vt[buf_][(vc + e) * 128 + sw] = p0;                        \
      bf16x2 p1; p1[0] = vreg[1][e]; p1[1] = vreg[3][e];                    \
      *(bf16x2*)&Vt[buf_][(vc + 8 + e) * 128 + sw] = p1;                    \
    }                                                                       \
  }

  bf16x8 vreg[4];

  // prologue: tile 0 -> buf 0
  STAGE_K(0, 0);
  LOAD_V(0);
  WRITE_V(0);
  __syncthreads();

  float mrL = 0.0f, lrL = 0.0f, mrH = 0.0f, lrH = 0.0f;
  f32x4 oL[4] = {}, oH[4] = {};

  for (int it = 0; it < nh; ++it) {
    const int c = it & 1;
    const bool pre = (it + 1 < nh);

    if (pre) {                       // prefetch tile it+1 into buf c^1
      STAGE_K((it + 1) * 128, c ^ 1);
      LOAD_V((it + 1) * 128);
    }

    attn_tile_step(Ks[c], Vt[c], bqH, qrowH, it * 128, it == nh - 1,
                   mrH, lrH, oH, l15, quad);
    if (it < nl)
      attn_tile_step(Ks[c], Vt[c], bqL, qrowL, it * 128, it == nl - 1,
                     mrL, lrL, oL, l15, quad);

    if (pre) {
      WRITE_V(c ^ 1);                // reg->LDS after compute (issue-early/write-late)
      __syncthreads();               // drains glds + V writes; publishes buf c^1
    }
  }

  // epilogues
  const float invL = 1.0f / lrL;
#pragma unroll
  for (int db = 0; db < 4; ++db) {
    bf16x4 o;
#pragma unroll
    for (int r = 0; r < 4; ++r) o[r] = (bf16)(oL[db][r] * invL);
    *(bf16x4*)(O + heado + (size_t)qrowL * H_ + db * 16 + quad * 4) = o;
  }
  const float invH = 1.0f / lrH;
#pragma unroll
  for (int db = 0; db < 4; ++db) {
    bf16x4 o;
#pragma unroll
    for (int r = 0; r < 4; ++r) o[r] = (bf16)(oH[db][r] * invH);
    *(bf16x4*)(O + heado + (size_t)qrowH * H_ + db * 16 + quad * 4) = o;
  }
#undef STAGE_K
#undef LOAD_V
#undef WRITE_V
}

extern "C" void kernel_launch(void* const* d_in, const int* in_sizes, int n_in,
                              void* d_out, int out_size, void* d_ws, size_t ws_size,
                              hipStream_t stream) {
  const float* hs = (const float*)d_in[0];
  const float* Wq = (const float*)d_in[1]; const float* bq = (const float*)d_in[2];
  const float* Wk = (const float*)d_in[3]; const float* bk = (const float*)d_in[4];
  const float* Wv = (const float*)d_in[5]; const float* bv = (const float*)d_in[6];
  const float* Wo = (const float*)d_in[7]; const float* bo = (const float*)d_in[8];
  float* out = (float*)d_out;

  const size_t elems = (size_t)B_ * S_ * H_;   // 4,194,304
  const size_t wel   = (size_t)H_ * H_;        // 1,048,576
  // workspace (40 MB): [hsb | AO aliased 8MB][Wq|Wk|Wv|Wo bf16 8MB][Ycat 24MB]
  bf16* hsb  = (bf16*)d_ws;     // read by QKV GEMM
  bf16* AO   = hsb;             // written by attn (hsb dead by then)
  bf16* Wqb  = hsb + elems;     // Wq;Wk;Wv contiguous = fused Wc
  bf16* Wkb  = Wqb + wel;
  bf16* Wvb  = Wkb + wel;
  bf16* Wob  = Wvb + wel;
  bf16* Ycat = Wob + wel;       // [4096][3072] fused Q|K|V

  cvt_f32_bf16<<<dim3(2048, 5), dim3(256), 0, stream>>>(
      hs, hsb, (int)elems, Wq, Wqb, Wk, Wkb, Wv, Wvb, Wo, Wob, (int)wel);

  const int M = B_ * S_;   // 4096
  const float QSCL = 0.125f * 1.44269504f;   // (1/sqrt(64)) * log2(e)

  gemm_qkv_8ph<<<dim3(192), dim3(512), 0, stream>>>(
      hsb, Wqb, bq, bk, bv, Ycat, QSCL);

  attn_causal<<<dim3(512), dim3(256), 0, stream>>>(Ycat, AO);

  gemm_bt_bias<float><<<dim3(H_ / 128, M / 128, 1), dim3(256), 0, stream>>>(
      AO, Wob, Wob, Wob, bo, bo, bo, out, out, out, 1.0f, 1.0f, 1.0f, M, H_, H_);
}